// Round 1
// baseline (417.632 us; speedup 1.0000x reference)
//
#include <hip/hip_runtime.h>
#include <hip/hip_bf16.h>

#define D_    1024
#define H_    16
#define HD_   64
#define RANK_ 256
#define B_    4
#define N_    2048

typedef __attribute__((ext_vector_type(8))) short bf16x8;
typedef __attribute__((ext_vector_type(4))) float f32x4;
typedef __attribute__((ext_vector_type(8))) unsigned short u16x8;

__device__ __forceinline__ unsigned short f2bf(float f) {
  unsigned int u = __float_as_uint(f);
  u += 0x7FFF + ((u >> 16) & 1);   // round-to-nearest-even
  return (unsigned short)(u >> 16);
}

__device__ __forceinline__ void gl_lds16(const void* g, void* l) {
  __builtin_amdgcn_global_load_lds(
      (const __attribute__((address_space(1))) unsigned int*)g,
      (__attribute__((address_space(3))) unsigned int*)l,
      16, 0, 0);
}

// ---------------- fp32 -> bf16 convert ----------------
__global__ __launch_bounds__(256)
void k_cvt(const float* __restrict__ in, unsigned short* __restrict__ out, int n4) {
  int i = blockIdx.x * 256 + threadIdx.x;
  if (i < n4) {
    float4 v = ((const float4*)in)[i];
    union { unsigned short s[4]; unsigned long long u; } r;
    r.s[0] = f2bf(v.x); r.s[1] = f2bf(v.y); r.s[2] = f2bf(v.z); r.s[3] = f2bf(v.w);
    ((unsigned long long*)out)[i] = r.u;
  }
}

// ---------------- GEMM: C[M,N] = A[M,K] * W[N,K]^T + bias ----------------
__device__ __forceinline__ void storeC(float* C, size_t idx, float v) { C[idx] = v; }
__device__ __forceinline__ void storeC(unsigned short* C, size_t idx, float v) { C[idx] = f2bf(v); }

template<typename OUT_T>
__global__ __launch_bounds__(256)
void k_gemm_bt(const unsigned short* __restrict__ A,
               const unsigned short* __restrict__ Bw,
               const float* __restrict__ bias,
               OUT_T* __restrict__ C,
               int M, int N, int K) {
  __shared__ unsigned short As[128 * 32];
  __shared__ unsigned short Bs[128 * 32];
  const int tid  = threadIdx.x;
  const int lane = tid & 63;
  const int wid  = tid >> 6;
  const int wm   = wid >> 1, wn = wid & 1;
  const int m0   = blockIdx.y * 128;
  const int n0   = blockIdx.x * 128;

  f32x4 acc[4][4] = {};

  const int srow = tid >> 2;          // 0..63 (4 threads per 32-col row)
  const int scol = (tid & 3) * 8;     // 0,8,16,24
  const size_t abase  = (size_t)(m0 + srow) * K + scol;
  const size_t abase2 = (size_t)(m0 + 64 + srow) * K + scol;
  const size_t bbase  = (size_t)(n0 + srow) * K + scol;
  const size_t bbase2 = (size_t)(n0 + 64 + srow) * K + scol;
  const int le = tid * 8;             // lds element offset, chunk 0

  for (int kt = 0; kt < K; kt += 32) {
    gl_lds16(A + abase + kt,  &As[le]);
    gl_lds16(A + abase2 + kt, &As[2048 + le]);
    gl_lds16(Bw + bbase + kt,  &Bs[le]);
    gl_lds16(Bw + bbase2 + kt, &Bs[2048 + le]);
    __syncthreads();

    const int ko = (lane >> 4) * 8;
    bf16x8 af[4], bfr[4];
#pragma unroll
    for (int i = 0; i < 4; ++i)
      af[i] = *(const bf16x8*)&As[(wm * 64 + i * 16 + (lane & 15)) * 32 + ko];
#pragma unroll
    for (int j = 0; j < 4; ++j)
      bfr[j] = *(const bf16x8*)&Bs[(wn * 64 + j * 16 + (lane & 15)) * 32 + ko];
#pragma unroll
    for (int i = 0; i < 4; ++i)
#pragma unroll
      for (int j = 0; j < 4; ++j)
        acc[i][j] = __builtin_amdgcn_mfma_f32_16x16x32_bf16(af[i], bfr[j], acc[i][j], 0, 0, 0);
    __syncthreads();
  }

  // epilogue: C row = m0+wm*64+i*16+(lane>>4)*4+r, col = n0+wn*64+j*16+(lane&15)
  const int r0 = m0 + wm * 64 + ((lane >> 4) * 4);
  const int c0 = n0 + wn * 64 + (lane & 15);
#pragma unroll
  for (int j = 0; j < 4; ++j) {
    float bj = bias[c0 + j * 16];
#pragma unroll
    for (int i = 0; i < 4; ++i)
#pragma unroll
      for (int r = 0; r < 4; ++r) {
        float v = acc[i][j][r] + bj;
        storeC(C, (size_t)(r0 + i * 16 + r) * N + (c0 + j * 16), v);
      }
  }
}

// ---------------- V transpose: v[b][n][h*64+d] -> vt[(b*H+h)][d][n] ----------------
__global__ __launch_bounds__(256)
void k_transpose_v(const unsigned short* __restrict__ V, unsigned short* __restrict__ Vt) {
  __shared__ unsigned short L[64][72];
  const int t  = threadIdx.x;
  const int n0 = blockIdx.x * 64;
  const int bh = blockIdx.y;
  const int b  = bh >> 4, h = bh & 15;
#pragma unroll
  for (int q = 0; q < 2; ++q) {
    int row = q * 32 + (t >> 3);
    int col = (t & 7) * 8;
    u16x8 v = *(const u16x8*)(V + (size_t)(b * N_ + n0 + row) * D_ + h * 64 + col);
    *(u16x8*)&L[row][col] = v;
  }
  __syncthreads();
#pragma unroll
  for (int q = 0; q < 2; ++q) {
    int drow = q * 32 + (t >> 3);
    int ncol = (t & 7) * 8;
    u16x8 v;
#pragma unroll
    for (int j = 0; j < 8; ++j) v[j] = L[ncol + j][drow];
    *(u16x8*)(Vt + (size_t)(bh * 64 + drow) * N_ + n0 + ncol) = v;
  }
}

// ---------------- flash attention ----------------
__global__ __launch_bounds__(256)
void k_flash(const unsigned short* __restrict__ Q,
             const unsigned short* __restrict__ Kg,
             const unsigned short* __restrict__ Vt,
             unsigned short* __restrict__ O) {
  __shared__ unsigned short Ks[64 * 64];   // [k][d]
  __shared__ unsigned short Vs[64 * 64];   // [d][k]
  __shared__ unsigned short Ps[4][16 * 64];// per-wave P tile [q][k]
  const int tid  = threadIdx.x;
  const int lane = tid & 63;
  const int wid  = tid >> 6;
  const int qt   = blockIdx.x;
  const int bh   = blockIdx.y;
  const int b    = bh >> 4, h = bh & 15;
  const int q0   = qt * 64 + wid * 16;

  // Q fragments (A-operand): row = lane&15, k(d) = c*32 + (lane>>4)*8 + j
  bf16x8 qf[2];
  {
    const unsigned short* qp = Q + (size_t)(b * N_ + q0 + (lane & 15)) * D_ + h * 64 + ((lane >> 4) * 8);
    qf[0] = *(const bf16x8*)qp;
    qf[1] = *(const bf16x8*)(qp + 32);
  }

  float m_r[4], l_r[4];
#pragma unroll
  for (int r = 0; r < 4; ++r) { m_r[r] = -1e30f; l_r[r] = 0.f; }
  f32x4 o[4] = {};

  const int srow = tid >> 3;        // 0..31
  const int scol = (tid & 7) * 8;   // 0..56
  const int le   = tid * 8;
  const int ko   = (lane >> 4) * 8;

  for (int kv0 = 0; kv0 < N_; kv0 += 64) {
    gl_lds16(Kg + (size_t)(b * N_ + kv0 + srow) * D_ + h * 64 + scol,      &Ks[le]);
    gl_lds16(Kg + (size_t)(b * N_ + kv0 + 32 + srow) * D_ + h * 64 + scol, &Ks[2048 + le]);
    gl_lds16(Vt + (size_t)(bh * 64 + srow) * N_ + kv0 + scol,              &Vs[le]);
    gl_lds16(Vt + (size_t)(bh * 64 + 32 + srow) * N_ + kv0 + scol,         &Vs[2048 + le]);
    __syncthreads();

    // S = Q K^T  (per wave: 16 q-rows x 64 k-cols)
    f32x4 s[4] = {};
#pragma unroll
    for (int j = 0; j < 4; ++j) {
      const unsigned short* kb = &Ks[(j * 16 + (lane & 15)) * 64 + ko];
      s[j] = __builtin_amdgcn_mfma_f32_16x16x32_bf16(qf[0], *(const bf16x8*)kb,        s[j], 0, 0, 0);
      s[j] = __builtin_amdgcn_mfma_f32_16x16x32_bf16(qf[1], *(const bf16x8*)(kb + 32), s[j], 0, 0, 0);
    }
#pragma unroll
    for (int j = 0; j < 4; ++j) s[j] *= 0.125f;   // HD^-0.5

    // online softmax (rows spread as row=(lane>>4)*4+r, k = j*16 + (lane&15))
    float alpha[4];
#pragma unroll
    for (int r = 0; r < 4; ++r) {
      float mx = fmaxf(fmaxf(s[0][r], s[1][r]), fmaxf(s[2][r], s[3][r]));
#pragma unroll
      for (int off = 1; off <= 8; off <<= 1)
        mx = fmaxf(mx, __shfl_xor(mx, off));
      float mn = fmaxf(m_r[r], mx);
      alpha[r] = __expf(m_r[r] - mn);
      m_r[r] = mn;
    }
    float ps[4] = {0.f, 0.f, 0.f, 0.f};
#pragma unroll
    for (int j = 0; j < 4; ++j)
#pragma unroll
      for (int r = 0; r < 4; ++r) {
        float p = __expf(s[j][r] - m_r[r]);
        ps[r] += p;
        Ps[wid][((lane >> 4) * 4 + r) * 64 + j * 16 + (lane & 15)] = f2bf(p);
      }
#pragma unroll
    for (int r = 0; r < 4; ++r) {
      float v = ps[r];
#pragma unroll
      for (int off = 1; off <= 8; off <<= 1)
        v += __shfl_xor(v, off);
      l_r[r] = l_r[r] * alpha[r] + v;
    }
#pragma unroll
    for (int dj = 0; dj < 4; ++dj)
#pragma unroll
      for (int r = 0; r < 4; ++r)
        o[dj][r] *= alpha[r];

    // O += P V   (A = P[16q x 64k] from Ps, B = V[k][d] from Vs[d][k])
#pragma unroll
    for (int dj = 0; dj < 4; ++dj) {
#pragma unroll
      for (int c2 = 0; c2 < 2; ++c2) {
        bf16x8 pf = *(const bf16x8*)&Ps[wid][(lane & 15) * 64 + c2 * 32 + ko];
        bf16x8 vf = *(const bf16x8*)&Vs[(dj * 16 + (lane & 15)) * 64 + c2 * 32 + ko];
        o[dj] = __builtin_amdgcn_mfma_f32_16x16x32_bf16(pf, vf, o[dj], 0, 0, 0);
      }
    }
    __syncthreads();
  }

#pragma unroll
  for (int dj = 0; dj < 4; ++dj)
#pragma unroll
    for (int r = 0; r < 4; ++r) {
      int qrow = q0 + (lane >> 4) * 4 + r;
      int dcol = h * 64 + dj * 16 + (lane & 15);
      O[(size_t)(b * N_ + qrow) * D_ + dcol] = f2bf(o[dj][r] / l_r[r]);
    }
}

extern "C" void kernel_launch(void* const* d_in, const int* in_sizes, int n_in,
                              void* d_out, int out_size, void* d_ws, size_t ws_size,
                              hipStream_t stream) {
  const float* x  = (const float*)d_in[0];
  const float* Wq = (const float*)d_in[1];
  const float* bq = (const float*)d_in[2];
  const float* Wd = (const float*)d_in[3];
  const float* bd = (const float*)d_in[4];
  const float* Wk = (const float*)d_in[5];
  const float* bk = (const float*)d_in[6];
  const float* Wv = (const float*)d_in[7];
  const float* bv = (const float*)d_in[8];
  const float* Wo = (const float*)d_in[9];
  const float* bo = (const float*)d_in[10];
  float* out = (float*)d_out;

  unsigned short* ws  = (unsigned short*)d_ws;
  unsigned short* xb  = ws;                  // 8388608  (x bf16, reused as attn-out)
  unsigned short* qb  = xb  + 8388608;       // 8388608
  unsigned short* kvb = qb  + 8388608;       // 2097152
  unsigned short* kb  = kvb + 2097152;       // 8388608
  unsigned short* vb  = kb  + 8388608;       // 8388608
  unsigned short* vtb = vb  + 8388608;       // 8388608
  unsigned short* Wqb = vtb + 8388608;       // 1048576
  unsigned short* Wdb = Wqb + 1048576;       // 262144
  unsigned short* Wkb = Wdb + 262144;        // 262144
  unsigned short* Wvb = Wkb + 262144;        // 262144
  unsigned short* Wob = Wvb + 262144;        // 1048576
  unsigned short* aob = xb;                  // reuse: x dead after q/kv GEMMs

  auto cvt = [&](const float* in, unsigned short* o, int n) {
    int n4 = n / 4;
    k_cvt<<<dim3((n4 + 255) / 256), dim3(256), 0, stream>>>(in, o, n4);
  };
  cvt(x,  xb,  8388608);
  cvt(Wq, Wqb, 1048576);
  cvt(Wd, Wdb, 262144);
  cvt(Wk, Wkb, 262144);
  cvt(Wv, Wvb, 262144);
  cvt(Wo, Wob, 1048576);

  k_gemm_bt<unsigned short><<<dim3(8, 64), dim3(256), 0, stream>>>(xb,  Wqb, bq, qb,  8192, 1024, 1024);
  k_gemm_bt<unsigned short><<<dim3(2, 64), dim3(256), 0, stream>>>(xb,  Wdb, bd, kvb, 8192,  256, 1024);
  k_gemm_bt<unsigned short><<<dim3(8, 64), dim3(256), 0, stream>>>(kvb, Wkb, bk, kb,  8192, 1024,  256);
  k_gemm_bt<unsigned short><<<dim3(8, 64), dim3(256), 0, stream>>>(kvb, Wvb, bv, vb,  8192, 1024,  256);
  k_transpose_v<<<dim3(32, 64), dim3(256), 0, stream>>>(vb, vtb);
  k_flash<<<dim3(32, 64), dim3(256), 0, stream>>>(qb, kb, vtb, aob);
  k_gemm_bt<float><<<dim3(8, 64), dim3(256), 0, stream>>>(aob, Wob, bo, out, 8192, 1024, 1024);
}

// Round 2
// 356.962 us; speedup vs baseline: 1.1700x; 1.1700x over previous
//
#include <hip/hip_runtime.h>
#include <hip/hip_bf16.h>

#define D_    1024
#define H_    16
#define HD_   64
#define RANK_ 256
#define B_    4
#define N_    2048

typedef __attribute__((ext_vector_type(8))) short bf16x8;
typedef __attribute__((ext_vector_type(4))) float f32x4;
typedef __attribute__((ext_vector_type(8))) unsigned short u16x8;

__device__ __forceinline__ unsigned short f2bf(float f) {
  unsigned int u = __float_as_uint(f);
  u += 0x7FFF + ((u >> 16) & 1);   // round-to-nearest-even
  return (unsigned short)(u >> 16);
}

__device__ __forceinline__ void gl_lds16(const void* g, void* l) {
  __builtin_amdgcn_global_load_lds(
      (const __attribute__((address_space(1))) unsigned int*)g,
      (__attribute__((address_space(3))) unsigned int*)l,
      16, 0, 0);
}

// ---------------- fp32 -> bf16 convert ----------------
__global__ __launch_bounds__(256)
void k_cvt(const float* __restrict__ in, unsigned short* __restrict__ out, int n4) {
  int i = blockIdx.x * 256 + threadIdx.x;
  if (i < n4) {
    float4 v = ((const float4*)in)[i];
    union { unsigned short s[4]; unsigned long long u; } r;
    r.s[0] = f2bf(v.x); r.s[1] = f2bf(v.y); r.s[2] = f2bf(v.z); r.s[3] = f2bf(v.w);
    ((unsigned long long*)out)[i] = r.u;
  }
}

// ---------------- GEMM: C[M,N] = A[M,K] * W[N,K]^T + bias ----------------
__device__ __forceinline__ void storeC(float* C, size_t idx, float v) { C[idx] = v; }
__device__ __forceinline__ void storeC(unsigned short* C, size_t idx, float v) { C[idx] = f2bf(v); }

template<typename OUT_T>
__global__ __launch_bounds__(256)
void k_gemm_bt(const unsigned short* __restrict__ A,
               const unsigned short* __restrict__ Bw,
               const float* __restrict__ bias,
               OUT_T* __restrict__ C,
               int M, int N, int K) {
  __shared__ unsigned short As[128 * 32];
  __shared__ unsigned short Bs[128 * 32];
  const int tid  = threadIdx.x;
  const int lane = tid & 63;
  const int wid  = tid >> 6;
  const int wm   = wid >> 1, wn = wid & 1;
  const int m0   = blockIdx.y * 128;
  const int n0   = blockIdx.x * 128;

  f32x4 acc[4][4] = {};

  const int srow = tid >> 2;          // 0..63 (4 threads per 32-col row)
  const int scol = (tid & 3) * 8;     // 0,8,16,24
  const size_t abase  = (size_t)(m0 + srow) * K + scol;
  const size_t abase2 = (size_t)(m0 + 64 + srow) * K + scol;
  const size_t bbase  = (size_t)(n0 + srow) * K + scol;
  const size_t bbase2 = (size_t)(n0 + 64 + srow) * K + scol;
  const int le = tid * 8;             // lds element offset, chunk 0

  for (int kt = 0; kt < K; kt += 32) {
    gl_lds16(A + abase + kt,  &As[le]);
    gl_lds16(A + abase2 + kt, &As[2048 + le]);
    gl_lds16(Bw + bbase + kt,  &Bs[le]);
    gl_lds16(Bw + bbase2 + kt, &Bs[2048 + le]);
    __syncthreads();

    const int ko = (lane >> 4) * 8;
    bf16x8 af[4], bfr[4];
#pragma unroll
    for (int i = 0; i < 4; ++i)
      af[i] = *(const bf16x8*)&As[(wm * 64 + i * 16 + (lane & 15)) * 32 + ko];
#pragma unroll
    for (int j = 0; j < 4; ++j)
      bfr[j] = *(const bf16x8*)&Bs[(wn * 64 + j * 16 + (lane & 15)) * 32 + ko];
#pragma unroll
    for (int i = 0; i < 4; ++i)
#pragma unroll
      for (int j = 0; j < 4; ++j)
        acc[i][j] = __builtin_amdgcn_mfma_f32_16x16x32_bf16(af[i], bfr[j], acc[i][j], 0, 0, 0);
    __syncthreads();
  }

  const int r0 = m0 + wm * 64 + ((lane >> 4) * 4);
  const int c0 = n0 + wn * 64 + (lane & 15);
#pragma unroll
  for (int j = 0; j < 4; ++j) {
    float bj = bias[c0 + j * 16];
#pragma unroll
    for (int i = 0; i < 4; ++i)
#pragma unroll
      for (int r = 0; r < 4; ++r) {
        float v = acc[i][j][r] + bj;
        storeC(C, (size_t)(r0 + i * 16 + r) * N + (c0 + j * 16), v);
      }
  }
}

// ---------------- V transpose: v[b][n][h*64+d] -> vt[(b*H+h)][d][n] ----------------
__global__ __launch_bounds__(256)
void k_transpose_v(const unsigned short* __restrict__ V, unsigned short* __restrict__ Vt) {
  __shared__ unsigned short L[64][72];
  const int t  = threadIdx.x;
  const int n0 = blockIdx.x * 64;
  const int bh = blockIdx.y;
  const int b  = bh >> 4, h = bh & 15;
#pragma unroll
  for (int q = 0; q < 2; ++q) {
    int row = q * 32 + (t >> 3);
    int col = (t & 7) * 8;
    u16x8 v = *(const u16x8*)(V + (size_t)(b * N_ + n0 + row) * D_ + h * 64 + col);
    *(u16x8*)&L[row][col] = v;
  }
  __syncthreads();
#pragma unroll
  for (int q = 0; q < 2; ++q) {
    int drow = q * 32 + (t >> 3);
    int ncol = (t & 7) * 8;
    u16x8 v;
#pragma unroll
    for (int j = 0; j < 8; ++j) v[j] = L[ncol + j][drow];
    *(u16x8*)(Vt + (size_t)(bh * 64 + drow) * N_ + n0 + ncol) = v;
  }
}

// ---------------- flash attention (XOR-swizzled LDS, XCD-swizzled grid) ----------------
__global__ __launch_bounds__(256)
void k_flash(const unsigned short* __restrict__ Q,
             const unsigned short* __restrict__ Kg,
             const unsigned short* __restrict__ Vt,
             unsigned short* __restrict__ O) {
  __shared__ unsigned short Ks[64 * 64];   // [k][d], 16B-block-swizzled by row&7
  __shared__ unsigned short Vs[64 * 64];   // [d][k], swizzled
  __shared__ unsigned short Ps[4][16 * 64];// per-wave P tile [q][k], swizzled
  const int tid  = threadIdx.x;
  const int lane = tid & 63;
  const int wid  = tid >> 6;
  // XCD-aware bijective swizzle: 2048 blocks = 8 XCDs x 256; the 32 q-tiles
  // of one (b,h) land on one XCD so K/V stay in that XCD's L2.
  const int bid     = blockIdx.x;
  const int logical = (bid & 7) * 256 + (bid >> 3);
  const int bh      = logical >> 5;        // 0..63
  const int qt      = logical & 31;        // 0..31
  const int b    = bh >> 4, h = bh & 15;
  const int q0   = qt * 64 + wid * 16;
  const int g    = lane >> 4;              // 0..3
  const int m    = lane & 15;
  const int sw   = lane & 7;               // read-side swizzle (all read rows have row&7 == lane&7)

  // Q fragments (A-operand): row = m, k(d) = g*8 + j (+32)
  bf16x8 qf[2];
  {
    const unsigned short* qp = Q + (size_t)(b * N_ + q0 + m) * D_ + h * 64 + g * 8;
    qf[0] = *(const bf16x8*)qp;
    qf[1] = *(const bf16x8*)(qp + 32);
  }

  float m_r[4], l_r[4];
#pragma unroll
  for (int r = 0; r < 4; ++r) { m_r[r] = -1e30f; l_r[r] = 0.f; }
  f32x4 o[4] = {};

  const int srow = tid >> 3;                       // 0..31
  const int sblk = (tid & 7) ^ (srow & 7);         // pre-swizzled source 16B-block
  const int scol = sblk * 8;                       // element offset in 64-elem row
  const int le   = tid * 8;                        // linear LDS dest (element)

  for (int kv0 = 0; kv0 < N_; kv0 += 64) {
    gl_lds16(Kg + (size_t)(b * N_ + kv0 + srow) * D_ + h * 64 + scol,      &Ks[le]);
    gl_lds16(Kg + (size_t)(b * N_ + kv0 + 32 + srow) * D_ + h * 64 + scol, &Ks[2048 + le]);
    gl_lds16(Vt + (size_t)(bh * 64 + srow) * N_ + kv0 + scol,              &Vs[le]);
    gl_lds16(Vt + (size_t)(bh * 64 + 32 + srow) * N_ + kv0 + scol,         &Vs[2048 + le]);
    __syncthreads();

    // S = Q K^T  (per wave: 16 q-rows x 64 k-cols)
    f32x4 s[4] = {};
#pragma unroll
    for (int j = 0; j < 4; ++j) {
      const unsigned short* kr = &Ks[(j * 16 + m) * 64];
      const int bA = (g ^ sw) * 8;
      const int bB = ((g ^ sw) ^ 4) * 8;
      s[j] = __builtin_amdgcn_mfma_f32_16x16x32_bf16(qf[0], *(const bf16x8*)&kr[bA], s[j], 0, 0, 0);
      s[j] = __builtin_amdgcn_mfma_f32_16x16x32_bf16(qf[1], *(const bf16x8*)&kr[bB], s[j], 0, 0, 0);
    }
#pragma unroll
    for (int j = 0; j < 4; ++j) s[j] *= 0.125f;   // HD^-0.5

    // online softmax (C-rows spread as row = g*4+r, k-col = j*16+m)
    float alpha[4];
#pragma unroll
    for (int r = 0; r < 4; ++r) {
      float mx = fmaxf(fmaxf(s[0][r], s[1][r]), fmaxf(s[2][r], s[3][r]));
#pragma unroll
      for (int off = 1; off <= 8; off <<= 1)
        mx = fmaxf(mx, __shfl_xor(mx, off));
      float mn = fmaxf(m_r[r], mx);
      alpha[r] = __expf(m_r[r] - mn);
      m_r[r] = mn;
    }
    float ps[4] = {0.f, 0.f, 0.f, 0.f};
#pragma unroll
    for (int j = 0; j < 4; ++j)
#pragma unroll
      for (int r = 0; r < 4; ++r) {
        float p = __expf(s[j][r] - m_r[r]);
        ps[r] += p;
        const int prow = g * 4 + r;
        const int pblk = (j * 2 + (m >> 3)) ^ (prow & 7);
        Ps[wid][prow * 64 + pblk * 8 + (m & 7)] = f2bf(p);
      }
#pragma unroll
    for (int r = 0; r < 4; ++r) {
      float v = ps[r];
#pragma unroll
      for (int off = 1; off <= 8; off <<= 1)
        v += __shfl_xor(v, off);
      l_r[r] = l_r[r] * alpha[r] + v;
    }
#pragma unroll
    for (int dj = 0; dj < 4; ++dj)
#pragma unroll
      for (int r = 0; r < 4; ++r)
        o[dj][r] *= alpha[r];

    // O += P V   (A = P[16q x 64k] from Ps, B = V[k][d] from Vs[d][k])
#pragma unroll
    for (int dj = 0; dj < 4; ++dj) {
#pragma unroll
      for (int c2 = 0; c2 < 2; ++c2) {
        const int blk = ((c2 * 4 + g) ^ sw) * 8;
        bf16x8 pf = *(const bf16x8*)&Ps[wid][m * 64 + blk];
        bf16x8 vf = *(const bf16x8*)&Vs[(dj * 16 + m) * 64 + blk];
        o[dj] = __builtin_amdgcn_mfma_f32_16x16x32_bf16(pf, vf, o[dj], 0, 0, 0);
      }
    }
    __syncthreads();
  }

#pragma unroll
  for (int dj = 0; dj < 4; ++dj)
#pragma unroll
    for (int r = 0; r < 4; ++r) {
      int qrow = q0 + g * 4 + r;
      int dcol = h * 64 + dj * 16 + m;
      O[(size_t)(b * N_ + qrow) * D_ + dcol] = f2bf(o[dj][r] / l_r[r]);
    }
}

extern "C" void kernel_launch(void* const* d_in, const int* in_sizes, int n_in,
                              void* d_out, int out_size, void* d_ws, size_t ws_size,
                              hipStream_t stream) {
  const float* x  = (const float*)d_in[0];
  const float* Wq = (const float*)d_in[1];
  const float* bq = (const float*)d_in[2];
  const float* Wd = (const float*)d_in[3];
  const float* bd = (const float*)d_in[4];
  const float* Wk = (const float*)d_in[5];
  const float* bk = (const float*)d_in[6];
  const float* Wv = (const float*)d_in[7];
  const float* bv = (const float*)d_in[8];
  const float* Wo = (const float*)d_in[9];
  const float* bo = (const float*)d_in[10];
  float* out = (float*)d_out;

  unsigned short* ws  = (unsigned short*)d_ws;
  unsigned short* xb  = ws;                  // 8388608  (x bf16, reused as attn-out)
  unsigned short* qb  = xb  + 8388608;       // 8388608
  unsigned short* kvb = qb  + 8388608;       // 2097152
  unsigned short* kb  = kvb + 2097152;       // 8388608
  unsigned short* vb  = kb  + 8388608;       // 8388608
  unsigned short* vtb = vb  + 8388608;       // 8388608
  unsigned short* Wqb = vtb + 8388608;       // 1048576
  unsigned short* Wdb = Wqb + 1048576;       // 262144
  unsigned short* Wkb = Wdb + 262144;        // 262144
  unsigned short* Wvb = Wkb + 262144;        // 262144
  unsigned short* Wob = Wvb + 262144;        // 1048576
  unsigned short* aob = xb;                  // reuse: x dead after q/kv GEMMs

  auto cvt = [&](const float* in, unsigned short* o, int n) {
    int n4 = n / 4;
    k_cvt<<<dim3((n4 + 255) / 256), dim3(256), 0, stream>>>(in, o, n4);
  };
  cvt(x,  xb,  8388608);
  cvt(Wq, Wqb, 1048576);
  cvt(Wd, Wdb, 262144);
  cvt(Wk, Wkb, 262144);
  cvt(Wv, Wvb, 262144);
  cvt(Wo, Wob, 1048576);

  k_gemm_bt<unsigned short><<<dim3(8, 64), dim3(256), 0, stream>>>(xb,  Wqb, bq, qb,  8192, 1024, 1024);
  k_gemm_bt<unsigned short><<<dim3(2, 64), dim3(256), 0, stream>>>(xb,  Wdb, bd, kvb, 8192,  256, 1024);
  k_gemm_bt<unsigned short><<<dim3(8, 64), dim3(256), 0, stream>>>(kvb, Wkb, bk, kb,  8192, 1024,  256);
  k_gemm_bt<unsigned short><<<dim3(8, 64), dim3(256), 0, stream>>>(kvb, Wvb, bv, vb,  8192, 1024,  256);
  k_transpose_v<<<dim3(32, 64), dim3(256), 0, stream>>>(vb, vtb);
  k_flash<<<dim3(2048), dim3(256), 0, stream>>>(qb, kb, vtb, aob);
  k_gemm_bt<float><<<dim3(8, 64), dim3(256), 0, stream>>>(aob, Wob, bo, out, 8192, 1024, 1024);
}

// Round 3
// 295.156 us; speedup vs baseline: 1.4150x; 1.2094x over previous
//
#include <hip/hip_runtime.h>
#include <hip/hip_bf16.h>

#define D_    1024
#define H_    16
#define HD_   64
#define RANK_ 256
#define B_    4
#define N_    2048

typedef __attribute__((ext_vector_type(8))) short bf16x8;
typedef __attribute__((ext_vector_type(4))) float f32x4;
typedef __attribute__((ext_vector_type(16))) float f32x16;
typedef __attribute__((ext_vector_type(8))) unsigned short u16x8;

__device__ __forceinline__ unsigned short f2bf(float f) {
  unsigned int u = __float_as_uint(f);
  u += 0x7FFF + ((u >> 16) & 1);   // round-to-nearest-even
  return (unsigned short)(u >> 16);
}

__device__ __forceinline__ unsigned int pk2(float a, float b) {
  float2 t; t.x = a; t.y = b;
  __hip_bfloat162 h = __float22bfloat162_rn(t);
  union { __hip_bfloat162 h; unsigned int u; } cv; cv.h = h; return cv.u;
}

__device__ __forceinline__ void gl_lds16(const void* g, void* l) {
  __builtin_amdgcn_global_load_lds(
      (const __attribute__((address_space(1))) unsigned int*)g,
      (__attribute__((address_space(3))) unsigned int*)l,
      16, 0, 0);
}

// ---------------- fp32 -> bf16 convert ----------------
__global__ __launch_bounds__(256)
void k_cvt(const float* __restrict__ in, unsigned short* __restrict__ out, int n4) {
  int i = blockIdx.x * 256 + threadIdx.x;
  if (i < n4) {
    float4 v = ((const float4*)in)[i];
    union { unsigned short s[4]; unsigned long long u; } r;
    r.s[0] = f2bf(v.x); r.s[1] = f2bf(v.y); r.s[2] = f2bf(v.z); r.s[3] = f2bf(v.w);
    ((unsigned long long*)out)[i] = r.u;
  }
}

// ---------------- GEMM: C[M,N] = A[M,K] * W[N,K]^T + bias ----------------
__device__ __forceinline__ void storeC(float* C, size_t idx, float v) { C[idx] = v; }
__device__ __forceinline__ void storeC(unsigned short* C, size_t idx, float v) { C[idx] = f2bf(v); }

template<typename OUT_T>
__global__ __launch_bounds__(256)
void k_gemm_bt(const unsigned short* __restrict__ A,
               const unsigned short* __restrict__ Bw,
               const float* __restrict__ bias,
               OUT_T* __restrict__ C,
               int M, int N, int K) {
  __shared__ unsigned short As[128 * 32];
  __shared__ unsigned short Bs[128 * 32];
  const int tid  = threadIdx.x;
  const int lane = tid & 63;
  const int wid  = tid >> 6;
  const int wm   = wid >> 1, wn = wid & 1;
  const int m0   = blockIdx.y * 128;
  const int n0   = blockIdx.x * 128;

  f32x4 acc[4][4] = {};

  const int srow = tid >> 2;
  const int scol = (tid & 3) * 8;
  const size_t abase  = (size_t)(m0 + srow) * K + scol;
  const size_t abase2 = (size_t)(m0 + 64 + srow) * K + scol;
  const size_t bbase  = (size_t)(n0 + srow) * K + scol;
  const size_t bbase2 = (size_t)(n0 + 64 + srow) * K + scol;
  const int le = tid * 8;

  for (int kt = 0; kt < K; kt += 32) {
    gl_lds16(A + abase + kt,  &As[le]);
    gl_lds16(A + abase2 + kt, &As[2048 + le]);
    gl_lds16(Bw + bbase + kt,  &Bs[le]);
    gl_lds16(Bw + bbase2 + kt, &Bs[2048 + le]);
    __syncthreads();

    const int ko = (lane >> 4) * 8;
    bf16x8 af[4], bfr[4];
#pragma unroll
    for (int i = 0; i < 4; ++i)
      af[i] = *(const bf16x8*)&As[(wm * 64 + i * 16 + (lane & 15)) * 32 + ko];
#pragma unroll
    for (int j = 0; j < 4; ++j)
      bfr[j] = *(const bf16x8*)&Bs[(wn * 64 + j * 16 + (lane & 15)) * 32 + ko];
#pragma unroll
    for (int i = 0; i < 4; ++i)
#pragma unroll
      for (int j = 0; j < 4; ++j)
        acc[i][j] = __builtin_amdgcn_mfma_f32_16x16x32_bf16(af[i], bfr[j], acc[i][j], 0, 0, 0);
    __syncthreads();
  }

  const int r0 = m0 + wm * 64 + ((lane >> 4) * 4);
  const int c0 = n0 + wn * 64 + (lane & 15);
#pragma unroll
  for (int j = 0; j < 4; ++j) {
    float bj = bias[c0 + j * 16];
#pragma unroll
    for (int i = 0; i < 4; ++i)
#pragma unroll
      for (int r = 0; r < 4; ++r) {
        float v = acc[i][j][r] + bj;
        storeC(C, (size_t)(r0 + i * 16 + r) * N + (c0 + j * 16), v);
      }
  }
}

// ---------------- V transpose: v[b][n][h*64+d] -> vt[(b*H+h)][d][n] ----------------
__global__ __launch_bounds__(256)
void k_transpose_v(const unsigned short* __restrict__ V, unsigned short* __restrict__ Vt) {
  __shared__ unsigned short L[64][72];
  const int t  = threadIdx.x;
  const int n0 = blockIdx.x * 64;
  const int bh = blockIdx.y;
  const int b  = bh >> 4, h = bh & 15;
#pragma unroll
  for (int q = 0; q < 2; ++q) {
    int row = q * 32 + (t >> 3);
    int col = (t & 7) * 8;
    u16x8 v = *(const u16x8*)(V + (size_t)(b * N_ + n0 + row) * D_ + h * 64 + col);
    *(u16x8*)&L[row][col] = v;
  }
  __syncthreads();
#pragma unroll
  for (int q = 0; q < 2; ++q) {
    int drow = q * 32 + (t >> 3);
    int ncol = (t & 7) * 8;
    u16x8 v;
#pragma unroll
    for (int j = 0; j < 8; ++j) v[j] = L[ncol + j][drow];
    *(u16x8*)(Vt + (size_t)(bh * 64 + drow) * N_ + n0 + ncol) = v;
  }
}

// ---------------- flash attention: swapped-QK^T 32x32, in-register softmax ----------------
// Block = 4 waves x 32 q-rows = 128 q-rows. KV tile = 64.
// S^T = mfma_32x32x16(K, Q): lane holds S[q=lane&31][k-pattern], row-local softmax.
__global__ __launch_bounds__(256)
void k_flash(const unsigned short* __restrict__ Q,
             const unsigned short* __restrict__ Kg,
             const unsigned short* __restrict__ Vt,
             unsigned short* __restrict__ O) {
  __shared__ unsigned short Ks[64 * 64];   // [k][d], 16B-block XOR-swizzled by row&7
  __shared__ unsigned short Vs[64 * 64];   // [d][k], swizzled
  const int tid  = threadIdx.x;
  const int lane = tid & 63;
  const int wid  = tid >> 6;
  // XCD swizzle: 1024 blocks = 8 XCDs x 128
  const int bid     = blockIdx.x;
  const int logical = (bid & 7) * 128 + (bid >> 3);
  const int bh      = logical >> 4;        // 0..63
  const int qt      = logical & 15;        // 0..15
  const int b   = bh >> 4, h = bh & 15;
  const int hi  = lane >> 5;               // 0/1
  const int q   = lane & 31;               // q-row (and d-col for PV)
  const int sw  = lane & 7;
  const int q0  = qt * 128 + wid * 32;     // wave q-base

  // Q as B-operand: col=q, k(d) = c4*16 + hi*8 + j
  bf16x8 qf[4];
  {
    const unsigned short* qp = Q + (size_t)(b * N_ + q0 + q) * D_ + h * 64 + hi * 8;
    qf[0] = *(const bf16x8*)qp;
    qf[1] = *(const bf16x8*)(qp + 16);
    qf[2] = *(const bf16x8*)(qp + 32);
    qf[3] = *(const bf16x8*)(qp + 48);
  }

  f32x16 o0 = {0.f}, o1 = {0.f};     // O[q-pattern][d = dh*32 + q]
  float m2 = -1e30f, l = 0.f;        // running log2-max, sum (per q-row = lane&31)
  const float cs = 0.125f * 1.44269504088896f;  // scale * log2(e)

  const int srow = tid >> 3;                   // 0..31
  const int sblk = (tid & 7) ^ (srow & 7);     // pre-swizzled source 16B-block
  const int scol = sblk * 8;
  const int le   = tid * 8;

  for (int kv0 = 0; kv0 < N_; kv0 += 64) {
    gl_lds16(Kg + (size_t)(b * N_ + kv0 + srow) * D_ + h * 64 + scol,      &Ks[le]);
    gl_lds16(Kg + (size_t)(b * N_ + kv0 + 32 + srow) * D_ + h * 64 + scol, &Ks[2048 + le]);
    gl_lds16(Vt + (size_t)(bh * 64 + srow) * N_ + kv0 + scol,              &Vs[le]);
    gl_lds16(Vt + (size_t)(bh * 64 + 32 + srow) * N_ + kv0 + scol,         &Vs[2048 + le]);
    __syncthreads();

    // S^T = K Q^T over two 32-row k-subtiles; contraction over d (4 chunks of 16)
    f32x16 sa0 = {0.f}, sa1 = {0.f};
#pragma unroll
    for (int c4 = 0; c4 < 4; ++c4) {
      const int blk = ((c4 * 2 + hi) ^ sw) * 8;
      bf16x8 kf0 = *(const bf16x8*)&Ks[q * 64 + blk];
      bf16x8 kf1 = *(const bf16x8*)&Ks[(32 + q) * 64 + blk];
      sa0 = __builtin_amdgcn_mfma_f32_32x32x16_bf16(kf0, qf[c4], sa0, 0, 0, 0);
      sa1 = __builtin_amdgcn_mfma_f32_32x32x16_bf16(kf1, qf[c4], sa1, 0, 0, 0);
    }

    // row max (lane-local 32 values + cross-half exchange)
    float pmax = sa0[0];
#pragma unroll
    for (int r = 1; r < 16; ++r) pmax = fmaxf(pmax, sa0[r]);
#pragma unroll
    for (int r = 0; r < 16; ++r) pmax = fmaxf(pmax, sa1[r]);
    pmax = fmaxf(pmax, __shfl_xor(pmax, 32));
    float pm2 = pmax * cs;

    // defer-max (T13): rescale only when max grows past threshold (8 ln-units)
    if (!__all(pm2 - m2 <= 11.54f)) {
      float mnew  = fmaxf(m2, pm2);
      float alpha = exp2f(m2 - mnew);
      m2 = mnew;
      l *= alpha;
#pragma unroll
      for (int r2 = 0; r2 < 16; ++r2) {
        float a = __shfl(alpha, (r2 & 3) + 8 * (r2 >> 2) + hi * 4);
        o0[r2] *= a; o1[r2] *= a;
      }
    }

    // P = exp2(s*cs - m2), pack to bf16, redistribute halves, PV
    float ss = 0.f;
#pragma unroll
    for (int st = 0; st < 2; ++st) {
      float p[16];
#pragma unroll
      for (int r = 0; r < 16; ++r) {
        float sv = st ? sa1[r] : sa0[r];
        p[r] = exp2f(fmaf(sv, cs, -m2));
        ss += p[r];
      }
      unsigned int w0 = pk2(p[0],  p[1]),  w1 = pk2(p[2],  p[3]);
      unsigned int w2 = pk2(p[4],  p[5]),  w3 = pk2(p[6],  p[7]);
      unsigned int w4 = pk2(p[8],  p[9]),  w5 = pk2(p[10], p[11]);
      unsigned int w6 = pk2(p[12], p[13]), w7 = pk2(p[14], p[15]);
      unsigned int x0 = __shfl_xor((int)w0, 32), x1 = __shfl_xor((int)w1, 32);
      unsigned int x2 = __shfl_xor((int)w2, 32), x3 = __shfl_xor((int)w3, 32);
      unsigned int x4 = __shfl_xor((int)w4, 32), x5 = __shfl_xor((int)w5, 32);
      unsigned int x6 = __shfl_xor((int)w6, 32), x7 = __shfl_xor((int)w7, 32);
      union { unsigned int u[4]; bf16x8 v; } fA, fB;
      fA.u[0] = hi ? x2 : w0;  fA.u[1] = hi ? x3 : w1;
      fA.u[2] = hi ? w2 : x0;  fA.u[3] = hi ? w3 : x1;
      fB.u[0] = hi ? x6 : w4;  fB.u[1] = hi ? x7 : w5;
      fB.u[2] = hi ? w6 : x4;  fB.u[3] = hi ? w7 : x5;

      // PV: A = P (row=q), B = V^T rows (col=d), contraction k = st*32 + kc*16 + hi*8 + j
      {
        const int blkA = ((st * 4 + 0 + hi) ^ sw) * 8;
        const int blkB = ((st * 4 + 2 + hi) ^ sw) * 8;
        bf16x8 v00 = *(const bf16x8*)&Vs[q * 64 + blkA];
        bf16x8 v01 = *(const bf16x8*)&Vs[q * 64 + blkB];
        bf16x8 v10 = *(const bf16x8*)&Vs[(32 + q) * 64 + blkA];
        bf16x8 v11 = *(const bf16x8*)&Vs[(32 + q) * 64 + blkB];
        o0 = __builtin_amdgcn_mfma_f32_32x32x16_bf16(fA.v, v00, o0, 0, 0, 0);
        o0 = __builtin_amdgcn_mfma_f32_32x32x16_bf16(fB.v, v01, o0, 0, 0, 0);
        o1 = __builtin_amdgcn_mfma_f32_32x32x16_bf16(fA.v, v10, o1, 0, 0, 0);
        o1 = __builtin_amdgcn_mfma_f32_32x32x16_bf16(fB.v, v11, o1, 0, 0, 0);
      }
    }
    ss += __shfl_xor(ss, 32);
    l += ss;
    __syncthreads();
  }

  // epilogue: O[q0 + (r2&3)+8*(r2>>2)+4*hi][h*64 + dh*32 + q] /= l[row]
  float linv = 1.0f / l;
#pragma unroll
  for (int r2 = 0; r2 < 16; ++r2) {
    const int qp_ = (r2 & 3) + 8 * (r2 >> 2);
    float li = __shfl(linv, qp_ + hi * 4);
    const int qq = q0 + qp_ + hi * 4;
    unsigned short* op = O + (size_t)(b * N_ + qq) * D_ + h * 64 + q;
    op[0]  = f2bf(o0[r2] * li);
    op[32] = f2bf(o1[r2] * li);
  }
}

extern "C" void kernel_launch(void* const* d_in, const int* in_sizes, int n_in,
                              void* d_out, int out_size, void* d_ws, size_t ws_size,
                              hipStream_t stream) {
  const float* x  = (const float*)d_in[0];
  const float* Wq = (const float*)d_in[1];
  const float* bq = (const float*)d_in[2];
  const float* Wd = (const float*)d_in[3];
  const float* bd = (const float*)d_in[4];
  const float* Wk = (const float*)d_in[5];
  const float* bk = (const float*)d_in[6];
  const float* Wv = (const float*)d_in[7];
  const float* bv = (const float*)d_in[8];
  const float* Wo = (const float*)d_in[9];
  const float* bo = (const float*)d_in[10];
  float* out = (float*)d_out;

  unsigned short* ws  = (unsigned short*)d_ws;
  unsigned short* xb  = ws;                  // 8388608  (x bf16, reused as attn-out)
  unsigned short* qb  = xb  + 8388608;       // 8388608
  unsigned short* kvb = qb  + 8388608;       // 2097152
  unsigned short* kb  = kvb + 2097152;       // 8388608
  unsigned short* vb  = kb  + 8388608;       // 8388608
  unsigned short* vtb = vb  + 8388608;       // 8388608
  unsigned short* Wqb = vtb + 8388608;       // 1048576
  unsigned short* Wdb = Wqb + 1048576;       // 262144
  unsigned short* Wkb = Wdb + 262144;        // 262144
  unsigned short* Wvb = Wkb + 262144;        // 262144
  unsigned short* Wob = Wvb + 262144;        // 1048576
  unsigned short* aob = xb;                  // reuse: x dead after q/kv GEMMs

  auto cvt = [&](const float* in, unsigned short* o, int n) {
    int n4 = n / 4;
    k_cvt<<<dim3((n4 + 255) / 256), dim3(256), 0, stream>>>(in, o, n4);
  };
  cvt(x,  xb,  8388608);
  cvt(Wq, Wqb, 1048576);
  cvt(Wd, Wdb, 262144);
  cvt(Wk, Wkb, 262144);
  cvt(Wv, Wvb, 262144);
  cvt(Wo, Wob, 1048576);

  k_gemm_bt<unsigned short><<<dim3(8, 64), dim3(256), 0, stream>>>(xb,  Wqb, bq, qb,  8192, 1024, 1024);
  k_gemm_bt<unsigned short><<<dim3(2, 64), dim3(256), 0, stream>>>(xb,  Wdb, bd, kvb, 8192,  256, 1024);
  k_gemm_bt<unsigned short><<<dim3(8, 64), dim3(256), 0, stream>>>(kvb, Wkb, bk, kb,  8192, 1024,  256);
  k_gemm_bt<unsigned short><<<dim3(8, 64), dim3(256), 0, stream>>>(kvb, Wvb, bv, vb,  8192, 1024,  256);
  k_transpose_v<<<dim3(32, 64), dim3(256), 0, stream>>>(vb, vtb);
  k_flash<<<dim3(1024), dim3(256), 0, stream>>>(qb, kb, vtb, aob);
  k_gemm_bt<float><<<dim3(8, 64), dim3(256), 0, stream>>>(aob, Wob, bo, out, 8192, 1024, 1024);
}